// Round 4
// baseline (125.717 us; speedup 1.0000x reference)
//
#include <hip/hip_runtime.h>
#include <hip/hip_bf16.h>
#include <hip/hip_cooperative_groups.h>

namespace cg = cooperative_groups;

// Problem: B=32, D=2048, NB=16, BS=512 (fp32 I/O)
//   out[b,r] = g[b, r>>7] * dot(W[r,:], x[b,:]) + bias[r]
//   g = sigmoid(x @ gate_w + gate_b); zero the 8 smallest gates per sample.
//
// ONE cooperative launch, 256 blocks x 256 threads (all co-resident):
//   Phase A: blocks 0..31 compute gates[32][16] -> ws  (~1 us)
//   grid.sync()
//   Phase B: block bi owns rows [bi*8, bi*8+8) x all 32 batches, full K.
//            4 waves split K (512 each), MFMA 16x16x32 bf16 (fp32 loads, RNE cvt),
//            LDS-reduce wave partials, epilogue g*s+bias -> out. No atomics.

#define D_DIM 2048
#define B_DIM 32
#define NB_DIM 16

typedef __attribute__((ext_vector_type(4))) float f32x4;
typedef __attribute__((ext_vector_type(8))) float f32x8;
typedef __attribute__((ext_vector_type(8))) __bf16 bf16x8;

static __device__ __forceinline__ __bf16 f2bf(float f) {
    unsigned u = __builtin_bit_cast(unsigned, f);
    u += 0x7fffu + ((u >> 16) & 1u);           // round-to-nearest-even
    unsigned short h = (unsigned short)(u >> 16);
    return __builtin_bit_cast(__bf16, h);
}

static __device__ __forceinline__ bf16x8 load_cvt8(const float* p) {
    const f32x8 v = *(const f32x8*)p;          // 32B: two dwordx4
    bf16x8 r;
#pragma unroll
    for (int i = 0; i < 8; ++i) r[i] = f2bf(v[i]);
    return r;
}

__global__ __launch_bounds__(256) void fused_kernel(
    const float* __restrict__ X,    // [32][2048]
    const float* __restrict__ GW,   // [2048][16]
    const float* __restrict__ GB,   // [16]
    const float* __restrict__ W,    // [2048][2048]
    const float* __restrict__ bias, // [2048]
    float* __restrict__ gates,      // ws: [32][16]
    float* __restrict__ out)        // [32][2048]
{
    __shared__ float smem[NB_DIM * 256 + NB_DIM];   // phase A: red[16][256] + sg[16]; phase B: red[4][8][32]
    const int t = threadIdx.x;

    // ---------------- Phase A: gates (blocks 0..31) ----------------
    if (blockIdx.x < B_DIM) {
        float* red = smem;                  // [16][256]
        float* sg  = smem + NB_DIM * 256;   // [16]
        const int b = blockIdx.x;

        float acc[NB_DIM];
#pragma unroll
        for (int n = 0; n < NB_DIM; ++n) acc[n] = 0.f;

#pragma unroll
        for (int i = 0; i < D_DIM / 256; ++i) {
            const int c = t + i * 256;
            const float xv = X[b * D_DIM + c];
            const float* gw = GW + c * NB_DIM;
#pragma unroll
            for (int n = 0; n < NB_DIM; ++n) acc[n] += xv * gw[n];
        }
#pragma unroll
        for (int n = 0; n < NB_DIM; ++n) red[n * 256 + t] = acc[n];
        __syncthreads();
        for (int s = 128; s > 0; s >>= 1) {
            if (t < s) {
#pragma unroll
                for (int n = 0; n < NB_DIM; ++n) red[n * 256 + t] += red[n * 256 + t + s];
            }
            __syncthreads();
        }
        if (t < NB_DIM) {
            const float v = red[t * 256] + GB[t];
            sg[t] = 1.f / (1.f + __expf(-v));
        }
        __syncthreads();
        if (t < NB_DIM) {
            const float g = sg[t];
            int rank = 0;  // gates smaller (ties: lower index smaller, matches lax.top_k drop)
#pragma unroll
            for (int m = 0; m < NB_DIM; ++m) {
                const float gm = sg[m];
                if (gm < g || (gm == g && m < t)) rank++;
            }
            gates[b * NB_DIM + t] = (rank >= NB_DIM / 2) ? g : 0.f;
        }
        __threadfence();   // make gates visible device-wide before grid sync
    }

    cg::this_grid().sync();

    // ---------------- Phase B: GEMM, 8 rows x 32 batches per block ----------------
    const int bi   = blockIdx.x;          // 0..255
    const int r0   = bi * 8;
    const int nblk = r0 >> 7;             // gate block for all 8 rows (8-row tile never crosses 128)
    const int wave = t >> 6;
    const int lane = t & 63;
    const int l15  = lane & 15;
    const int q    = lane >> 4;
    const int row8 = l15 & 7;             // rows duplicated into 16x16 MFMA tile (M=8 used)

    const int kb = wave * (D_DIM / 4);    // 512 per wave

    const float* arow = W + (size_t)(r0 + row8) * D_DIM + kb + q * 8;
    const float* b0p  = X + (size_t)(l15)       * D_DIM + kb + q * 8;
    const float* b1p  = X + (size_t)(l15 + 16)  * D_DIM + kb + q * 8;

    f32x4 acc0 = {0.f, 0.f, 0.f, 0.f};
    f32x4 acc1 = {0.f, 0.f, 0.f, 0.f};

#pragma unroll
    for (int s = 0; s < 16; ++s) {        // 16 MFMA k-steps of 32
        const bf16x8 av  = load_cvt8(arow + s * 32);
        const bf16x8 bv0 = load_cvt8(b0p  + s * 32);
        const bf16x8 bv1 = load_cvt8(b1p  + s * 32);
        acc0 = __builtin_amdgcn_mfma_f32_16x16x32_bf16(av, bv0, acc0, 0, 0, 0);
        acc1 = __builtin_amdgcn_mfma_f32_16x16x32_bf16(av, bv1, acc1, 0, 0, 0);
    }

    // C/D layout: col = lane&15 (batch), row m = q*4 + i (W-row offset). Rows 8..15 are
    // duplicates of 0..7 -> only q<2 lanes hold valid rows.
    __syncthreads();                      // smem handoff from phase A (blocks 0..31)
    float* red = smem;                    // [4][8][32] = wave, row, batch
    if (q < 2) {
#pragma unroll
        for (int i = 0; i < 4; ++i) {
            red[wave * 256 + (q * 4 + i) * 32 + l15]      = acc0[i];
            red[wave * 256 + (q * 4 + i) * 32 + 16 + l15] = acc1[i];
        }
    }
    __syncthreads();

    // epilogue: thread t -> (row = t>>5, b = t&31)
    const int row = t >> 5;
    const int b   = t & 31;
    const float s = red[row * 32 + b] + red[256 + row * 32 + b] +
                    red[512 + row * 32 + b] + red[768 + row * 32 + b];
    const float g = gates[b * NB_DIM + nblk];
    out[(size_t)b * D_DIM + r0 + row] = g * s + bias[r0 + row];
}

extern "C" void kernel_launch(void* const* d_in, const int* in_sizes, int n_in,
                              void* d_out, int out_size, void* d_ws, size_t ws_size,
                              hipStream_t stream) {
    const float* x    = (const float*)d_in[0];  // [32][2048]
    const float* gw   = (const float*)d_in[1];  // [2048][16]
    const float* gb   = (const float*)d_in[2];  // [16]
    const float* w    = (const float*)d_in[3];  // [2048][2048]
    const float* bias = (const float*)d_in[4];  // [2048]
    float* out   = (float*)d_out;
    float* gates = (float*)d_ws;                // 32*16 fp32

    void* args[] = {(void*)&x, (void*)&gw, (void*)&gb, (void*)&w, (void*)&bias,
                    (void*)&gates, (void*)&out};
    hipLaunchCooperativeKernel((const void*)fused_kernel, dim3(256), dim3(256),
                               args, 0, stream);
}

// Round 5
// 91.288 us; speedup vs baseline: 1.3772x; 1.3772x over previous
//
#include <hip/hip_runtime.h>
#include <hip/hip_bf16.h>

// Problem: B=32, D=2048, NB=16, BS=512 (fp32 I/O)
//   out[b,r] = g[b, r>>7] * dot(W[r,:], x[b,:]) + bias[r]
//   g = sigmoid(x @ gate_w + gate_b); zero the 8 smallest gates per sample.
//
// 2 plain launches (no atomics, no cooperative, no partials round-trip):
//   K1 (32 blocks):  gates[32][16] -> ws ; X converted to bf16 -> ws (128 KB)
//   K2 (512 blocks): block owns 4 rows x 32 batches, full K. 4 waves K-split 512,
//                    MFMA 16x16x32 bf16 (A: W cvt on the fly, B: Xbf direct),
//                    2 KB LDS reduce, epilogue g*s+bias -> out.

#define D_DIM 2048
#define B_DIM 32
#define NB_DIM 16

typedef __attribute__((ext_vector_type(4))) float f32x4;
typedef __attribute__((ext_vector_type(8))) float f32x8;
typedef __attribute__((ext_vector_type(8))) __bf16 bf16x8;

static __device__ __forceinline__ __bf16 f2bf(float f) {
    unsigned u = __builtin_bit_cast(unsigned, f);
    u += 0x7fffu + ((u >> 16) & 1u);           // round-to-nearest-even
    unsigned short h = (unsigned short)(u >> 16);
    return __builtin_bit_cast(__bf16, h);
}

static __device__ __forceinline__ bf16x8 load_cvt8(const float* p) {
    const f32x8 v = *(const f32x8*)p;          // 32B: two dwordx4
    bf16x8 r;
#pragma unroll
    for (int i = 0; i < 8; ++i) r[i] = f2bf(v[i]);
    return r;
}

// ---------------- Kernel 1: gates + X->bf16 ----------------
__global__ __launch_bounds__(256) void prep_kernel(
    const float* __restrict__ X,    // [32][2048]
    const float* __restrict__ GW,   // [2048][16]
    const float* __restrict__ GB,   // [16]
    float* __restrict__ gates,      // ws: [32][16]
    __bf16* __restrict__ Xbf)       // ws: [32][2048]
{
    __shared__ float red[NB_DIM][256];
    __shared__ float sg[NB_DIM];
    const int b = blockIdx.x;
    const int t = threadIdx.x;

    // convert this sample's X row to bf16 (coalesced 32B loads / 16B stores)
    {
        const int idx = b * D_DIM + t * 8;
        *(bf16x8*)(Xbf + idx) = load_cvt8(X + idx);
    }

    float acc[NB_DIM];
#pragma unroll
    for (int n = 0; n < NB_DIM; ++n) acc[n] = 0.f;

#pragma unroll
    for (int i = 0; i < D_DIM / 256; ++i) {
        const int c = t + i * 256;
        const float xv = X[b * D_DIM + c];
        const float* gw = GW + c * NB_DIM;
#pragma unroll
        for (int n = 0; n < NB_DIM; ++n) acc[n] += xv * gw[n];
    }
#pragma unroll
    for (int n = 0; n < NB_DIM; ++n) red[n][t] = acc[n];
    __syncthreads();
    for (int s = 128; s > 0; s >>= 1) {
        if (t < s) {
#pragma unroll
            for (int n = 0; n < NB_DIM; ++n) red[n][t] += red[n][t + s];
        }
        __syncthreads();
    }
    if (t < NB_DIM) {
        const float v = red[t][0] + GB[t];
        sg[t] = 1.f / (1.f + __expf(-v));
    }
    __syncthreads();
    if (t < NB_DIM) {
        const float g = sg[t];
        int rank = 0;  // gates smaller (ties: lower index smaller, matches lax.top_k drop)
#pragma unroll
        for (int m = 0; m < NB_DIM; ++m) {
            const float gm = sg[m];
            if (gm < g || (gm == g && m < t)) rank++;
        }
        gates[b * NB_DIM + t] = (rank >= NB_DIM / 2) ? g : 0.f;
    }
}

// ---------------- Kernel 2: GEMM, 4 rows x 32 batches per block ----------------
// 512 blocks (2/CU, 8 waves/CU). Wave w handles K-slice [w*512, +512) for all
// 4 rows x 32 batches. A-frag rows duplicated 4x into the 16x16 tile (m&3 = row);
// within each lane-group q, reg i holds row i, so q-groups are exact duplicates:
// only q==0 writes LDS. C/D: col = lane&15 (batch), row m = q*4 + i.
__global__ __launch_bounds__(256) void gemm_kernel(
    const float* __restrict__ W,      // [2048][2048]
    const __bf16* __restrict__ Xbf,   // ws: [32][2048]
    const float* __restrict__ gates,  // ws: [32][16]
    const float* __restrict__ bias,   // [2048]
    float* __restrict__ out)          // [32][2048]
{
    __shared__ float red[4 * 4 * 32];             // [wave][row][batch] = 2 KB
    const int t    = threadIdx.x;
    const int r0   = blockIdx.x * 4;
    const int nblk = r0 >> 7;                     // 4-row tile never crosses a 128 block
    const int wave = t >> 6;
    const int lane = t & 63;
    const int l15  = lane & 15;
    const int q    = lane >> 4;

    const int kb = wave * (D_DIM / 4);            // 512 per wave

    const float*  arow = W   + (size_t)(r0 + (l15 & 3)) * D_DIM + kb + q * 8;
    const __bf16* b0p  = Xbf + (size_t)(l15)            * D_DIM + kb + q * 8;
    const __bf16* b1p  = Xbf + (size_t)(l15 + 16)       * D_DIM + kb + q * 8;

    f32x4 acc0 = {0.f, 0.f, 0.f, 0.f};
    f32x4 acc1 = {0.f, 0.f, 0.f, 0.f};

#pragma unroll
    for (int s = 0; s < 16; ++s) {                // 16 MFMA k-steps of 32
        const bf16x8 av  = load_cvt8(arow + s * 32);
        const bf16x8 bv0 = *(const bf16x8*)(b0p + s * 32);
        const bf16x8 bv1 = *(const bf16x8*)(b1p + s * 32);
        acc0 = __builtin_amdgcn_mfma_f32_16x16x32_bf16(av, bv0, acc0, 0, 0, 0);
        acc1 = __builtin_amdgcn_mfma_f32_16x16x32_bf16(av, bv1, acc1, 0, 0, 0);
    }

    if (q == 0) {
#pragma unroll
        for (int i = 0; i < 4; ++i) {
            red[wave * 128 + i * 32 + l15]      = acc0[i];
            red[wave * 128 + i * 32 + 16 + l15] = acc1[i];
        }
    }
    __syncthreads();

    // epilogue: 32 threads, thread b writes 4 consecutive rows as f32x4
    if (t < B_DIM) {
        const int b = t;
        f32x4 s;
#pragma unroll
        for (int i = 0; i < 4; ++i) {
            s[i] = red[0 * 128 + i * 32 + b] + red[1 * 128 + i * 32 + b] +
                   red[2 * 128 + i * 32 + b] + red[3 * 128 + i * 32 + b];
        }
        const float g = gates[b * NB_DIM + nblk];
        const f32x4 bi = *(const f32x4*)(bias + r0);
        f32x4 y;
#pragma unroll
        for (int i = 0; i < 4; ++i) y[i] = g * s[i] + bi[i];
        *(f32x4*)(out + (size_t)b * D_DIM + r0) = y;
    }
}

extern "C" void kernel_launch(void* const* d_in, const int* in_sizes, int n_in,
                              void* d_out, int out_size, void* d_ws, size_t ws_size,
                              hipStream_t stream) {
    const float* x    = (const float*)d_in[0];  // [32][2048]
    const float* gw   = (const float*)d_in[1];  // [2048][16]
    const float* gb   = (const float*)d_in[2];  // [16]
    const float* w    = (const float*)d_in[3];  // [2048][2048]
    const float* bias = (const float*)d_in[4];  // [2048]
    float* out = (float*)d_out;

    __bf16* Xbf  = (__bf16*)d_ws;                               // 32*2048*2B = 128 KB
    float* gates = (float*)((char*)d_ws + (size_t)B_DIM * D_DIM * sizeof(__bf16));

    prep_kernel<<<B_DIM, 256, 0, stream>>>(x, gw, gb, gates, Xbf);
    gemm_kernel<<<D_DIM / 4, 256, 0, stream>>>(w, Xbf, gates, bias, out);
}